// Round 1
// baseline (124.809 us; speedup 1.0000x reference)
//
#include <hip/hip_runtime.h>

#define HWSZ 16384
#define WW 128
#define HH 128
#define CC 64
#define NIMG 8
#define NPLANE 512      // n*C
#define NCHW 8388608    // 8*64*128*128
#define BN_EPS 1e-5f

// ---------------- Kernel 1: per-(n,c) spatial mean ----------------
__global__ __launch_bounds__(256) void mean_kernel(const float* __restrict__ x,
                                                   float* __restrict__ means) {
    int plane = blockIdx.x;                       // 0..511
    const float4* xp = (const float4*)(x + (size_t)plane * HWSZ);
    float s = 0.f;
    // 4096 float4 per plane, 256 threads -> 16 iters
    for (int i = threadIdx.x; i < HWSZ / 4; i += 256) {
        float4 v = xp[i];
        s += v.x + v.y + v.z + v.w;
    }
    // wave(64) reduction
    for (int off = 32; off > 0; off >>= 1)
        s += __shfl_down(s, off, 64);
    __shared__ float wsum[4];
    int wave = threadIdx.x >> 6;
    if ((threadIdx.x & 63) == 0) wsum[wave] = s;
    __syncthreads();
    if (threadIdx.x == 0) {
        float t = wsum[0] + wsum[1] + wsum[2] + wsum[3];
        means[plane] = t * (1.0f / (float)HWSZ);
    }
}

// ------- Kernel 2: 1x1 conv (64-dot) + BN(eval) + softmax over 9 -------
__global__ __launch_bounds__(576) void filter_kernel(const float* __restrict__ means,
                                                     const float* __restrict__ conv_w,
                                                     const float* __restrict__ gamma,
                                                     const float* __restrict__ beta,
                                                     const float* __restrict__ bn_mean,
                                                     const float* __restrict__ bn_var,
                                                     float* __restrict__ wgt) {
    int nimg = blockIdx.x;     // 0..7
    int j = threadIdx.x;       // 0..575  (= c*9 + k)
    __shared__ float sm[CC];
    __shared__ float sv[576];
    if (j < CC) sm[j] = means[nimg * CC + j];
    __syncthreads();
    const float* wr = conv_w + j * CC;   // conv_w[j, :], row-major (576,64)
    float dot = 0.f;
#pragma unroll
    for (int c = 0; c < CC; ++c) dot += sm[c] * wr[c];
    float g = gamma[j] * rsqrtf(bn_var[j] + BN_EPS);
    float v = (dot - bn_mean[j]) * g + beta[j];
    sv[j] = v;
    __syncthreads();
    int base = (j / 9) * 9;
    float m = sv[base];
#pragma unroll
    for (int t = 1; t < 9; ++t) m = fmaxf(m, sv[base + t]);
    float den = 0.f;
#pragma unroll
    for (int t = 0; t < 9; ++t) den += __expf(sv[base + t] - m);
    wgt[nimg * 576 + j] = __expf(v - m) / den;
}

// ------- Kernel 3: dynamic 3x3 reflect-pad conv + residual, float4 I/O -------
__global__ __launch_bounds__(256) void conv_kernel(const float* __restrict__ x,
                                                   const float* __restrict__ wgt,
                                                   float* __restrict__ out) {
    int plane = blockIdx.x >> 4;       // (n*C + c)
    int rb    = blockIdx.x & 15;       // row block (8 rows each)
    int tid   = threadIdx.x;
    int r  = tid >> 5;                 // 0..7
    int q  = tid & 31;                 // quad index along width
    int h  = rb * 8 + r;
    int w0 = q * 4;

    __shared__ float sw[9];
    if (tid < 9) sw[tid] = wgt[plane * 9 + tid];
    __syncthreads();

    const float* xp = x + (size_t)plane * HWSZ;
    int hm = (h == 0)   ? 1   : h - 1;   // reflect: -1 -> 1
    int hp = (h == 127) ? 126 : h + 1;   // reflect: 128 -> 126
    int rows[3] = {hm, h, hp};

    float V[3][6];   // columns w0-1 .. w0+4
#pragma unroll
    for (int ri = 0; ri < 3; ++ri) {
        const float* rowp = xp + rows[ri] * WW;
        float4 c4 = *(const float4*)(rowp + w0);
        V[ri][1] = c4.x; V[ri][2] = c4.y; V[ri][3] = c4.z; V[ri][4] = c4.w;
        V[ri][0] = (w0 == 0)   ? rowp[1]   : rowp[w0 - 1];   // reflect -1 -> 1
        V[ri][5] = (w0 == 124) ? rowp[126] : rowp[w0 + 4];   // reflect 128 -> 126
    }

    float o[4];
#pragma unroll
    for (int p = 0; p < 4; ++p) {
        float acc = 0.f;
#pragma unroll
        for (int ri = 0; ri < 3; ++ri)
#pragma unroll
            for (int t = 0; t < 3; ++t)
                acc = fmaf(sw[ri * 3 + t], V[ri][p + t], acc);
        o[p] = acc;
    }

    size_t base = (size_t)plane * HWSZ + (size_t)h * WW + w0;
    float4 ov = {o[0], o[1], o[2], o[3]};
    *(float4*)(out + base) = ov;
    float4 dv = {V[1][1] - o[0], V[1][2] - o[1], V[1][3] - o[2], V[1][4] - o[3]};
    *(float4*)(out + NCHW + base) = dv;
}

extern "C" void kernel_launch(void* const* d_in, const int* in_sizes, int n_in,
                              void* d_out, int out_size, void* d_ws, size_t ws_size,
                              hipStream_t stream) {
    const float* x       = (const float*)d_in[0];
    const float* conv_w  = (const float*)d_in[1];
    const float* gamma   = (const float*)d_in[2];
    const float* beta    = (const float*)d_in[3];
    const float* bn_mean = (const float*)d_in[4];
    const float* bn_var  = (const float*)d_in[5];
    float* out = (float*)d_out;

    float* means = (float*)d_ws;          // 512 floats
    float* wgt   = means + NPLANE;        // 4608 floats

    mean_kernel<<<NPLANE, 256, 0, stream>>>(x, means);
    filter_kernel<<<NIMG, 576, 0, stream>>>(means, conv_w, gamma, beta, bn_mean, bn_var, wgt);
    conv_kernel<<<NPLANE * 16, 256, 0, stream>>>(x, wgt, out);
}

// Round 3
// 119.989 us; speedup vs baseline: 1.0402x; 1.0402x over previous
//
#include <hip/hip_runtime.h>

#define WW 128
#define HWSZ 16384
#define CC 64
#define NPLANE 512
#define NCHW 8388608      // 8*64*128*128
#define BN_EPS 1e-5f

// ---------------- Kernel 1: per-(n,c) spatial mean ----------------
__global__ __launch_bounds__(256) void dc_mean_kernel(const float* __restrict__ x,
                                                      float* __restrict__ means) {
    const int plane = blockIdx.x;                 // 0..511
    const float4* xp = (const float4*)(x + (size_t)plane * HWSZ);
    float s = 0.f;
#pragma unroll
    for (int i = 0; i < 16; ++i) {                // 4096 float4 / 256 thr
        float4 v = xp[threadIdx.x + i * 256];
        s += v.x + v.y + v.z + v.w;
    }
    for (int off = 32; off > 0; off >>= 1)
        s += __shfl_down(s, off, 64);
    __shared__ float wsum[4];
    if ((threadIdx.x & 63) == 0) wsum[threadIdx.x >> 6] = s;
    __syncthreads();
    if (threadIdx.x == 0)
        means[plane] = (wsum[0] + wsum[1] + wsum[2] + wsum[3]) * (1.0f / 16384.0f);
}

// ---- Kernel 2: per-block filter recompute + dynamic 3x3 reflect conv ----
__global__ __launch_bounds__(256) void dc_conv_kernel(const float* __restrict__ x,
                                                      const float* __restrict__ means,
                                                      const float* __restrict__ conv_w,
                                                      const float* __restrict__ gamma,
                                                      const float* __restrict__ beta,
                                                      const float* __restrict__ bn_mean,
                                                      const float* __restrict__ bn_var,
                                                      float* __restrict__ out) {
    const int plane = blockIdx.x >> 4;            // n*64 + c
    const int rb    = blockIdx.x & 15;            // 8-row band
    const int tid   = threadIdx.x;
    const int n = plane >> 6;
    const int c = plane & 63;

    // ---- prologue: 9 logits + softmax for this plane (redundant per block) ----
    __shared__ float sm[CC];
    __shared__ float lv[9];
    __shared__ float sw9[9];
    if (tid < CC) sm[tid] = means[n * CC + tid];
    __syncthreads();
    if (tid < 9) {
        const int j = c * 9 + tid;
        const float4* wr = (const float4*)(conv_w + j * CC);  // (576,64) row-major
        float dot = 0.f;
#pragma unroll
        for (int q = 0; q < 16; ++q) {
            float4 wv = wr[q];
            dot += sm[q * 4 + 0] * wv.x + sm[q * 4 + 1] * wv.y
                 + sm[q * 4 + 2] * wv.z + sm[q * 4 + 3] * wv.w;
        }
        const float g = gamma[j] * rsqrtf(bn_var[j] + BN_EPS);
        lv[tid] = (dot - bn_mean[j]) * g + beta[j];
    }
    __syncthreads();
    if (tid < 9) {
        float m = lv[0];
#pragma unroll
        for (int t = 1; t < 9; ++t) m = fmaxf(m, lv[t]);
        float den = 0.f;
#pragma unroll
        for (int t = 0; t < 9; ++t) den += __expf(lv[t] - m);
        sw9[tid] = __expf(lv[tid] - m) / den;
    }
    __syncthreads();

    float w9[9];
#pragma unroll
    for (int t = 0; t < 9; ++t) w9[t] = sw9[t];

    // ---- conv over this block's 8 rows ----
    const int r  = tid >> 5;                      // 0..7
    const int q  = tid & 31;
    const int h  = rb * 8 + r;
    const int w0 = q * 4;

    const float* xpl = x + (size_t)plane * HWSZ;
    const int hm = (h == 0)   ? 1   : h - 1;      // reflect -1 -> 1
    const int hp = (h == 127) ? 126 : h + 1;      // reflect 128 -> 126
    const int rows[3] = {hm, h, hp};

    float V[3][6];
#pragma unroll
    for (int ri = 0; ri < 3; ++ri) {
        const float* rowp = xpl + rows[ri] * WW;
        float4 c4 = *(const float4*)(rowp + w0);
        V[ri][1] = c4.x; V[ri][2] = c4.y; V[ri][3] = c4.z; V[ri][4] = c4.w;
        V[ri][0] = (w0 == 0)   ? rowp[1]   : rowp[w0 - 1];
        V[ri][5] = (w0 == 124) ? rowp[126] : rowp[w0 + 4];
    }

    float o[4];
#pragma unroll
    for (int p = 0; p < 4; ++p) {
        float acc = 0.f;
#pragma unroll
        for (int ri = 0; ri < 3; ++ri)
#pragma unroll
            for (int t = 0; t < 3; ++t)
                acc = fmaf(w9[ri * 3 + t], V[ri][p + t], acc);
        o[p] = acc;
    }

    const size_t base = (size_t)plane * HWSZ + (size_t)h * WW + w0;
    float4 ov = {o[0], o[1], o[2], o[3]};
    *(float4*)(out + base) = ov;
    float4 dv = {V[1][1] - o[0], V[1][2] - o[1], V[1][3] - o[2], V[1][4] - o[3]};
    *(float4*)(out + NCHW + base) = dv;
}

extern "C" void kernel_launch(void* const* d_in, const int* in_sizes, int n_in,
                              void* d_out, int out_size, void* d_ws, size_t ws_size,
                              hipStream_t stream) {
    const float* x       = (const float*)d_in[0];
    const float* conv_w  = (const float*)d_in[1];
    const float* gamma   = (const float*)d_in[2];
    const float* beta    = (const float*)d_in[3];
    const float* bn_mean = (const float*)d_in[4];
    const float* bn_var  = (const float*)d_in[5];
    float* out = (float*)d_out;
    float* means = (float*)d_ws;                  // 512 floats

    dc_mean_kernel<<<NPLANE, 256, 0, stream>>>(x, means);
    dc_conv_kernel<<<NPLANE * 16, 256, 0, stream>>>(x, means, conv_w, gamma, beta,
                                                    bn_mean, bn_var, out);
}

// Round 4
// 113.747 us; speedup vs baseline: 1.0973x; 1.0549x over previous
//
#include <hip/hip_runtime.h>

#define WW 128
#define HWSZ 16384
#define CC 64
#define NPLANE 512
#define NCHW 8388608      // 8*64*128*128
#define BN_EPS 1e-5f

// ---------------- Kernel 1: per-(n,c) spatial mean ----------------
__global__ __launch_bounds__(256) void dc_mean_kernel(const float* __restrict__ x,
                                                      float* __restrict__ means) {
    const int plane = blockIdx.x;                 // 0..511
    const float4* xp = (const float4*)(x + (size_t)plane * HWSZ);
    float s = 0.f;
#pragma unroll
    for (int i = 0; i < 16; ++i) {                // 4096 float4 / 256 thr
        float4 v = xp[threadIdx.x + i * 256];
        s += v.x + v.y + v.z + v.w;
    }
    for (int off = 32; off > 0; off >>= 1)
        s += __shfl_down(s, off, 64);
    __shared__ float wsum[4];
    if ((threadIdx.x & 63) == 0) wsum[threadIdx.x >> 6] = s;
    __syncthreads();
    if (threadIdx.x == 0)
        means[plane] = (wsum[0] + wsum[1] + wsum[2] + wsum[3]) * (1.0f / 16384.0f);
}

// ---- Kernel 2: fast filter prologue + dynamic 3x3 reflect conv (32 rows/blk) ----
__global__ __launch_bounds__(256) void dc_conv_kernel(const float* __restrict__ x,
                                                      const float* __restrict__ means,
                                                      const float* __restrict__ conv_w,
                                                      const float* __restrict__ gamma,
                                                      const float* __restrict__ beta,
                                                      const float* __restrict__ bn_mean,
                                                      const float* __restrict__ bn_var,
                                                      float* __restrict__ out) {
    const int plane = blockIdx.x >> 2;            // n*64 + c
    const int band  = blockIdx.x & 3;             // 32-row band
    const int tid   = threadIdx.x;
    const int n = plane >> 6;
    const int c = plane & 63;

    // ---- prologue: 144-thread cooperative 9x64 dot + BN, one sync ----
    __shared__ float lv[9];
    if (tid < 144) {
        const int j    = tid >> 4;                // tap 0..8
        const int part = tid & 15;                // 16 lanes per tap
        const int jj = c * 9 + j;
        float4 mv = *(const float4*)(means + n * CC + part * 4);
        float4 wv = *(const float4*)(conv_w + (size_t)jj * CC + part * 4);
        float d = mv.x * wv.x + mv.y * wv.y + mv.z * wv.z + mv.w * wv.w;
        d += __shfl_down(d, 8, 16);
        d += __shfl_down(d, 4, 16);
        d += __shfl_down(d, 2, 16);
        d += __shfl_down(d, 1, 16);
        if (part == 0) {
            const float g = gamma[jj] * rsqrtf(bn_var[jj] + BN_EPS);
            lv[j] = (d - bn_mean[jj]) * g + beta[jj];
        }
    }
    __syncthreads();

    // redundant per-thread softmax from LDS broadcast (no extra sync)
    float w9[9];
    {
        float m = lv[0];
#pragma unroll
        for (int t = 1; t < 9; ++t) m = fmaxf(m, lv[t]);
        float den = 0.f;
        float e[9];
#pragma unroll
        for (int t = 0; t < 9; ++t) { e[t] = __expf(lv[t] - m); den += e[t]; }
        const float inv = 1.0f / den;
#pragma unroll
        for (int t = 0; t < 9; ++t) w9[t] = e[t] * inv;
    }

    // ---- conv over this block's 32 rows ----
    const int r  = tid >> 5;                      // 0..7
    const int q  = tid & 31;
    const int w0 = q * 4;
    const float* xpl = x + (size_t)plane * HWSZ;

#pragma unroll
    for (int it = 0; it < 4; ++it) {
        const int h  = band * 32 + it * 8 + r;
        const int hm = (h == 0)   ? 1   : h - 1;  // reflect -1 -> 1
        const int hp = (h == 127) ? 126 : h + 1;  // reflect 128 -> 126
        const int rows[3] = {hm, h, hp};

        float V[3][6];
#pragma unroll
        for (int ri = 0; ri < 3; ++ri) {
            const float* rowp = xpl + rows[ri] * WW;
            float4 c4 = *(const float4*)(rowp + w0);
            V[ri][1] = c4.x; V[ri][2] = c4.y; V[ri][3] = c4.z; V[ri][4] = c4.w;
            // reflect: col -1 -> 1 (== c4.y at w0==0); col 128 -> 126 (== c4.z at w0==124)
            V[ri][0] = (w0 == 0)   ? c4.y : rowp[w0 - 1];
            V[ri][5] = (w0 == 124) ? c4.z : rowp[w0 + 4];
        }

        float o[4];
#pragma unroll
        for (int p = 0; p < 4; ++p) {
            float acc = 0.f;
#pragma unroll
            for (int ri = 0; ri < 3; ++ri)
#pragma unroll
                for (int t = 0; t < 3; ++t)
                    acc = fmaf(w9[ri * 3 + t], V[ri][p + t], acc);
            o[p] = acc;
        }

        const size_t base = (size_t)plane * HWSZ + (size_t)h * WW + w0;
        float4 ov = {o[0], o[1], o[2], o[3]};
        *(float4*)(out + base) = ov;
        float4 dv = {V[1][1] - o[0], V[1][2] - o[1], V[1][3] - o[2], V[1][4] - o[3]};
        *(float4*)(out + NCHW + base) = dv;
    }
}

extern "C" void kernel_launch(void* const* d_in, const int* in_sizes, int n_in,
                              void* d_out, int out_size, void* d_ws, size_t ws_size,
                              hipStream_t stream) {
    const float* x       = (const float*)d_in[0];
    const float* conv_w  = (const float*)d_in[1];
    const float* gamma   = (const float*)d_in[2];
    const float* beta    = (const float*)d_in[3];
    const float* bn_mean = (const float*)d_in[4];
    const float* bn_var  = (const float*)d_in[5];
    float* out = (float*)d_out;
    float* means = (float*)d_ws;                  // 512 floats

    dc_mean_kernel<<<NPLANE, 256, 0, stream>>>(x, means);
    dc_conv_kernel<<<NPLANE * 4, 256, 0, stream>>>(x, means, conv_w, gamma, beta,
                                                   bn_mean, bn_var, out);
}

// Round 6
// 108.338 us; speedup vs baseline: 1.1520x; 1.0499x over previous
//
#include <hip/hip_runtime.h>

#define WW 128
#define HWSZ 16384
#define CC 64
#define NPLANE 512
#define NCHW 8388608      // 8*64*128*128
#define BN_EPS 1e-5f

typedef float v4f __attribute__((ext_vector_type(4)));   // clang vector: OK for nontemporal builtins

// ---------------- Kernel 1: per-(n,c) spatial mean ----------------
__global__ __launch_bounds__(256) void dc_mean_kernel(const float* __restrict__ x,
                                                      float* __restrict__ means) {
    const int plane = blockIdx.x;                 // 0..511
    const v4f* xp = (const v4f*)(x + (size_t)plane * HWSZ);
    float s = 0.f;
#pragma unroll
    for (int i = 0; i < 16; ++i) {                // 4096 float4 / 256 thr
        v4f v = xp[threadIdx.x + i * 256];
        s += v.x + v.y + v.z + v.w;
    }
    for (int off = 32; off > 0; off >>= 1)
        s += __shfl_down(s, off, 64);
    __shared__ float wsum[4];
    if ((threadIdx.x & 63) == 0) wsum[threadIdx.x >> 6] = s;
    __syncthreads();
    if (threadIdx.x == 0)
        means[plane] = (wsum[0] + wsum[1] + wsum[2] + wsum[3]) * (1.0f / 16384.0f);
}

// ---- Kernel 2: filter prologue + rolling-row dynamic 3x3 reflect conv ----
// 64 rows per block; each thread owns 8 consecutive rows, 4 cols.
__global__ __launch_bounds__(256) void dc_conv_kernel(const float* __restrict__ x,
                                                      const float* __restrict__ means,
                                                      const float* __restrict__ conv_w,
                                                      const float* __restrict__ gamma,
                                                      const float* __restrict__ beta,
                                                      const float* __restrict__ bn_mean,
                                                      const float* __restrict__ bn_var,
                                                      float* __restrict__ out) {
    const int plane = blockIdx.x >> 1;            // n*64 + c
    const int band  = blockIdx.x & 1;             // 64-row band
    const int tid   = threadIdx.x;
    const int n = plane >> 6;
    const int c = plane & 63;

    // ---- prologue: 144-thread cooperative 9x64 dot + BN, one sync ----
    __shared__ float lv[9];
    if (tid < 144) {
        const int j    = tid >> 4;                // tap 0..8
        const int part = tid & 15;                // 16 lanes per tap
        const int jj = c * 9 + j;
        v4f mv = *(const v4f*)(means + n * CC + part * 4);
        v4f wv = *(const v4f*)(conv_w + (size_t)jj * CC + part * 4);
        float d = mv.x * wv.x + mv.y * wv.y + mv.z * wv.z + mv.w * wv.w;
        d += __shfl_down(d, 8, 16);
        d += __shfl_down(d, 4, 16);
        d += __shfl_down(d, 2, 16);
        d += __shfl_down(d, 1, 16);
        if (part == 0) {
            const float g = gamma[jj] * rsqrtf(bn_var[jj] + BN_EPS);
            lv[j] = (d - bn_mean[jj]) * g + beta[jj];
        }
    }
    __syncthreads();

    // redundant per-thread softmax from LDS broadcast
    float w9[9];
    {
        float m = lv[0];
#pragma unroll
        for (int t = 1; t < 9; ++t) m = fmaxf(m, lv[t]);
        float den = 0.f;
        float e[9];
#pragma unroll
        for (int t = 0; t < 9; ++t) { e[t] = __expf(lv[t] - m); den += e[t]; }
        const float inv = 1.0f / den;
#pragma unroll
        for (int t = 0; t < 9; ++t) w9[t] = e[t] * inv;
    }

    // ---- rolling-row conv: thread owns rows r0..r0+7, cols w0..w0+3 ----
    const int g  = tid >> 5;                      // row group 0..7
    const int q  = tid & 31;                      // lane within 32-wide segment
    const int w0 = q * 4;
    const int r0 = band * 64 + g * 8;
    const float* xpl = x + (size_t)plane * HWSZ;

    v4f cP, cC, cN, cX;
    float eP0, eP1, eC0, eC1, eN0, eN1, eX0, eX1;

#define LOADROW(R, c4, e0, e1)                                              \
    {                                                                       \
        int RR = ((R) < 0) ? 1 : (((R) > 127) ? 126 : (R));                 \
        c4 = *(const v4f*)(xpl + RR * WW + w0);                             \
        float lft = __shfl_up(c4.w, 1, 32);                                 \
        float rgt = __shfl_down(c4.x, 1, 32);                               \
        e0 = (w0 == 0)   ? c4.y : lft;   /* reflect col -1 -> 1   */        \
        e1 = (w0 == 124) ? c4.z : rgt;   /* reflect col 128 -> 126 */       \
    }

    LOADROW(r0 - 1, cP, eP0, eP1);
    LOADROW(r0,     cC, eC0, eC1);
    LOADROW(r0 + 1, cN, eN0, eN1);

#pragma unroll
    for (int i = 0; i < 8; ++i) {
        const int h = r0 + i;
        if (i < 7) { LOADROW(h + 2, cX, eX0, eX1); }   // pipelined prefetch

        const float VP[6] = {eP0, cP.x, cP.y, cP.z, cP.w, eP1};
        const float VC[6] = {eC0, cC.x, cC.y, cC.z, cC.w, eC1};
        const float VN[6] = {eN0, cN.x, cN.y, cN.z, cN.w, eN1};

        float o[4];
#pragma unroll
        for (int p = 0; p < 4; ++p) {
            float acc = 0.f;
#pragma unroll
            for (int t = 0; t < 3; ++t) {
                acc = fmaf(w9[t],     VP[p + t], acc);
                acc = fmaf(w9[3 + t], VC[p + t], acc);
                acc = fmaf(w9[6 + t], VN[p + t], acc);
            }
            o[p] = acc;
        }

        const size_t base = (size_t)plane * HWSZ + (size_t)h * WW + w0;
        v4f ov = {o[0], o[1], o[2], o[3]};
        v4f dv = {cC.x - o[0], cC.y - o[1], cC.z - o[2], cC.w - o[3]};
        __builtin_nontemporal_store(ov, (v4f*)(out + base));
        __builtin_nontemporal_store(dv, (v4f*)(out + NCHW + base));

        cP = cC; eP0 = eC0; eP1 = eC1;
        cC = cN; eC0 = eN0; eC1 = eN1;
        cN = cX; eN0 = eX0; eN1 = eX1;
    }
#undef LOADROW
}

extern "C" void kernel_launch(void* const* d_in, const int* in_sizes, int n_in,
                              void* d_out, int out_size, void* d_ws, size_t ws_size,
                              hipStream_t stream) {
    const float* x       = (const float*)d_in[0];
    const float* conv_w  = (const float*)d_in[1];
    const float* gamma   = (const float*)d_in[2];
    const float* beta    = (const float*)d_in[3];
    const float* bn_mean = (const float*)d_in[4];
    const float* bn_var  = (const float*)d_in[5];
    float* out = (float*)d_out;
    float* means = (float*)d_ws;                  // 512 floats

    dc_mean_kernel<<<NPLANE, 256, 0, stream>>>(x, means);
    dc_conv_kernel<<<NPLANE * 2, 256, 0, stream>>>(x, means, conv_w, gamma, beta,
                                                   bn_mean, bn_var, out);
}

// Round 7
// 106.528 us; speedup vs baseline: 1.1716x; 1.0170x over previous
//
#include <hip/hip_runtime.h>

#define WW 128
#define HWSZ 16384
#define CC 64
#define NPLANE 512
#define NCHW 8388608      // 8*64*128*128
#define BN_EPS 1e-5f

typedef float v4f __attribute__((ext_vector_type(4)));

// ------- Kernel 1: half-plane partial sums (2 blocks per plane) -------
__global__ __launch_bounds__(256) void dc_mean_kernel(const float* __restrict__ x,
                                                      float* __restrict__ partial) {
    const int b = blockIdx.x;                     // 0..1023 = plane*2 + half
    const v4f* xp = (const v4f*)(x + (size_t)b * (HWSZ / 2));
    float s = 0.f;
#pragma unroll
    for (int i = 0; i < 8; ++i) {                 // 2048 v4f / 256 thr
        v4f v = xp[threadIdx.x + i * 256];
        s += v.x + v.y + v.z + v.w;
    }
    for (int off = 32; off > 0; off >>= 1)
        s += __shfl_down(s, off, 64);
    __shared__ float wsum[4];
    if ((threadIdx.x & 63) == 0) wsum[threadIdx.x >> 6] = s;
    __syncthreads();
    if (threadIdx.x == 0)
        partial[b] = wsum[0] + wsum[1] + wsum[2] + wsum[3];
}

// ---- Kernel 2: filter prologue + rolling-row dynamic 3x3 reflect conv ----
// 32 rows per block (2048 blocks, 8/CU); each thread rolls 4 rows, 4 cols.
__global__ __launch_bounds__(256) void dc_conv_kernel(const float* __restrict__ x,
                                                      const float* __restrict__ partial,
                                                      const float* __restrict__ conv_w,
                                                      const float* __restrict__ gamma,
                                                      const float* __restrict__ beta,
                                                      const float* __restrict__ bn_mean,
                                                      const float* __restrict__ bn_var,
                                                      float* __restrict__ out) {
    const int plane = blockIdx.x >> 2;            // n*64 + c
    const int band  = blockIdx.x & 3;             // 32-row band
    const int tid   = threadIdx.x;
    const int n = plane >> 6;
    const int c = plane & 63;

    // ---- prologue: 144-thread cooperative 9x64 dot + BN, one sync ----
    __shared__ float lv[9];
    if (tid < 144) {
        const int j    = tid >> 4;                // tap 0..8
        const int part = tid & 15;                // 16 lanes per tap, 4 channels each
        const int jj = c * 9 + j;
        v4f pa = *(const v4f*)(partial + n * 128 + part * 8);
        v4f pb = *(const v4f*)(partial + n * 128 + part * 8 + 4);
        v4f wv = *(const v4f*)(conv_w + (size_t)jj * CC + part * 4);
        float d = (pa.x + pa.y) * wv.x + (pa.z + pa.w) * wv.y
                + (pb.x + pb.y) * wv.z + (pb.z + pb.w) * wv.w;
        d += __shfl_down(d, 8, 16);
        d += __shfl_down(d, 4, 16);
        d += __shfl_down(d, 2, 16);
        d += __shfl_down(d, 1, 16);
        if (part == 0) {
            d *= (1.0f / 16384.0f);               // sum -> mean
            const float g = gamma[jj] * rsqrtf(bn_var[jj] + BN_EPS);
            lv[j] = (d - bn_mean[jj]) * g + beta[jj];
        }
    }
    __syncthreads();

    // redundant per-thread softmax from LDS broadcast
    float w9[9];
    {
        float m = lv[0];
#pragma unroll
        for (int t = 1; t < 9; ++t) m = fmaxf(m, lv[t]);
        float den = 0.f;
        float e[9];
#pragma unroll
        for (int t = 0; t < 9; ++t) { e[t] = __expf(lv[t] - m); den += e[t]; }
        const float inv = 1.0f / den;
#pragma unroll
        for (int t = 0; t < 9; ++t) w9[t] = e[t] * inv;
    }

    // ---- rolling-row conv: thread owns rows r0..r0+3, cols w0..w0+3 ----
    const int g  = tid >> 5;                      // row group 0..7 (4 rows each)
    const int q  = tid & 31;
    const int w0 = q * 4;
    const int r0 = band * 32 + g * 4;
    const float* xpl = x + (size_t)plane * HWSZ;

    v4f cP, cC, cN, cX;
    float eP0, eP1, eC0, eC1, eN0, eN1, eX0, eX1;

#define LOADROW(R, c4, e0, e1)                                              \
    {                                                                       \
        int RR = ((R) < 0) ? 1 : (((R) > 127) ? 126 : (R));                 \
        c4 = *(const v4f*)(xpl + RR * WW + w0);                             \
        float lft = __shfl_up(c4.w, 1, 32);                                 \
        float rgt = __shfl_down(c4.x, 1, 32);                               \
        e0 = (w0 == 0)   ? c4.y : lft;   /* reflect col -1 -> 1   */        \
        e1 = (w0 == 124) ? c4.z : rgt;   /* reflect col 128 -> 126 */       \
    }

    LOADROW(r0 - 1, cP, eP0, eP1);
    LOADROW(r0,     cC, eC0, eC1);
    LOADROW(r0 + 1, cN, eN0, eN1);

#pragma unroll
    for (int i = 0; i < 4; ++i) {
        const int h = r0 + i;
        if (i < 3) { LOADROW(h + 2, cX, eX0, eX1); }   // pipelined prefetch

        const float VP[6] = {eP0, cP.x, cP.y, cP.z, cP.w, eP1};
        const float VC[6] = {eC0, cC.x, cC.y, cC.z, cC.w, eC1};
        const float VN[6] = {eN0, cN.x, cN.y, cN.z, cN.w, eN1};

        float o[4];
#pragma unroll
        for (int p = 0; p < 4; ++p) {
            float acc = 0.f;
#pragma unroll
            for (int t = 0; t < 3; ++t) {
                acc = fmaf(w9[t],     VP[p + t], acc);
                acc = fmaf(w9[3 + t], VC[p + t], acc);
                acc = fmaf(w9[6 + t], VN[p + t], acc);
            }
            o[p] = acc;
        }

        const size_t base = (size_t)plane * HWSZ + (size_t)h * WW + w0;
        v4f ov = {o[0], o[1], o[2], o[3]};
        v4f dv = {cC.x - o[0], cC.y - o[1], cC.z - o[2], cC.w - o[3]};
        __builtin_nontemporal_store(ov, (v4f*)(out + base));
        __builtin_nontemporal_store(dv, (v4f*)(out + NCHW + base));

        cP = cC; eP0 = eC0; eP1 = eC1;
        cC = cN; eC0 = eN0; eC1 = eN1;
        cN = cX; eN0 = eX0; eN1 = eX1;
    }
#undef LOADROW
}

extern "C" void kernel_launch(void* const* d_in, const int* in_sizes, int n_in,
                              void* d_out, int out_size, void* d_ws, size_t ws_size,
                              hipStream_t stream) {
    const float* x       = (const float*)d_in[0];
    const float* conv_w  = (const float*)d_in[1];
    const float* gamma   = (const float*)d_in[2];
    const float* beta    = (const float*)d_in[3];
    const float* bn_mean = (const float*)d_in[4];
    const float* bn_var  = (const float*)d_in[5];
    float* out = (float*)d_out;
    float* partial = (float*)d_ws;                // 1024 floats

    dc_mean_kernel<<<NPLANE * 2, 256, 0, stream>>>(x, partial);
    dc_conv_kernel<<<NPLANE * 4, 256, 0, stream>>>(x, partial, conv_w, gamma, beta,
                                                   bn_mean, bn_var, out);
}